// Round 16
// baseline (161.996 us; speedup 1.0000x reference)
//
#include <hip/hip_runtime.h>
#include <hip/hip_fp8.h>

typedef float  float4_t __attribute__((ext_vector_type(4)));
typedef unsigned int uint2_t __attribute__((ext_vector_type(2)));
typedef float  f32x4   __attribute__((ext_vector_type(4)));

#define FEAT   256
#define BANK   2048
#define NROWS  2048       // 256 anchors * 8 views
#define NPAN   576        // 64-col panels over 36864 cols
#define NCLS   18
#define CSPLIT 16         // m-chunks per class for csum atomics
#define EXP2K  14.4269504088896f   // 10*log2(e); A pre-scaled -> exp(10 dot)=exp2(acc)
#define A_CH8  65536      // A 8-byte chunks: 64 strips * 2 mi * 8 ks * 64 lanes
#define B_CH8  1179648    // B 8-byte chunks: 576 panels * 32 frags * 64 lanes
#define TOT8   (A_CH8 + B_CH8)

__device__ inline unsigned char to_fp8(float x) {
    __hip_fp8_e4m3 f(x);
    return *reinterpret_cast<unsigned char*>(&f);
}

// 16-lane (DPP row) sum: every lane of each 16-lane group gets the group total.
__device__ inline float rowsum16(float x) {
    float t;
    asm("s_nop 1\n\tv_add_f32 %0, %1, %1 row_ror:1"  : "=v"(t) : "v"(x)); x = t;
    asm("s_nop 1\n\tv_add_f32 %0, %1, %1 row_ror:2"  : "=v"(t) : "v"(x)); x = t;
    asm("s_nop 1\n\tv_add_f32 %0, %1, %1 row_ror:4"  : "=v"(t) : "v"(x)); x = t;
    asm("s_nop 1\n\tv_add_f32 %0, %1, %1 row_ror:8"  : "=v"(t) : "v"(x)); x = t;
    return x;
}

// Pass 0: fp32 -> fp8 e4m3 ONCE, MFMA fragment order; A pre-scaled by EXP2K.
// Also zeroes out[0] and csum[18*256].
__global__ __launch_bounds__(256) void pass0_pack(
    const float* __restrict__ X,    // X_anchor [256][8][256]
    const float* __restrict__ Q,    // queue [19][2048][256]
    unsigned char* __restrict__ Abuf,
    unsigned char* __restrict__ Bbuf,
    float* __restrict__ csum,
    float* __restrict__ out)
{
    const int cid = blockIdx.x * 256 + threadIdx.x;
    if (cid == 0) out[0] = 0.0f;
    if (cid < NCLS * FEAT) csum[cid] = 0.0f;
    if (cid >= TOT8) return;
    const int lane = cid & 63;
    const int ks   = (cid >> 6) & 7;
    const int k    = ks * 32 + ((lane >> 4) << 3);
    const float* src;
    unsigned char* dst;
    float scale;
    if (cid < A_CH8) {
        const int mi = (cid >> 9) & 1, s = cid >> 10;
        const int r  = s * 32 + mi * 16 + (lane & 15);      // anchor row = v*256+a
        src = X + ((size_t)((r & 255) * 8 + (r >> 8))) * FEAT + k;
        dst = Abuf + ((size_t)cid << 3);
        scale = EXP2K;
    } else {
        const int b = cid - A_CH8;
        const int ni = (b >> 9) & 3, p = b >> 11;
        const int col = p * 64 + ni * 16 + (lane & 15);     // class 0 skipped
        src = Q + ((size_t)(BANK + col)) * FEAT + k;
        dst = Bbuf + ((size_t)b << 3);
        scale = 1.0f;
    }
    float4_t v0 = *(const float4_t*)src;
    float4_t v1 = *(const float4_t*)(src + 4);
    const unsigned int b0 = to_fp8(v0.x * scale) | ((unsigned int)to_fp8(v0.y * scale) << 8)
                          | ((unsigned int)to_fp8(v0.z * scale) << 16) | ((unsigned int)to_fp8(v0.w * scale) << 24);
    const unsigned int b1 = to_fp8(v1.x * scale) | ((unsigned int)to_fp8(v1.y * scale) << 8)
                          | ((unsigned int)to_fp8(v1.z * scale) << 16) | ((unsigned int)to_fp8(v1.w * scale) << 24);
    uint2_t u = { b0, b1 };
    *(uint2_t*)dst = u;
}

// Pass 2: per-class column sums of Q (f32), 16 m-chunks per class, atomicAdd
// into csum[c][k] (16-way contention per address: negligible).
__global__ __launch_bounds__(256) void pass2_csum(
    const float* __restrict__ Q, float* __restrict__ csum)
{
    const int c = blockIdx.x >> 4;        // 0..17 -> class c+1
    const int i = blockIdx.x & 15;
    const int k = threadIdx.x;
    const float* base = Q + ((size_t)(c + 1) * BANK + (size_t)i * (BANK / CSPLIT)) * FEAT + k;
    float s = 0.0f;
    #pragma unroll 4
    for (int m = 0; m < BANK / CSPLIT; ++m) s += base[(size_t)m * FEAT];
    atomicAdd(&csum[c * FEAT + k], s);
}

// Pass 1: barrier-free streaming fp8 GEMM, 1024-thread blocks (16 waves) so
// 2 blocks/CU = 32 waves = full static residency. Per-wave work identical to
// R15 (A 32 rows x K=256 pinned, 3 panels, divergence-free exp2 epilogue).
__global__ __launch_bounds__(1024, 8) void pass1_gemm(
    const unsigned char* __restrict__ Abuf,
    const unsigned char* __restrict__ Bbuf,
    float* __restrict__ partS)  // [NROWS][NPAN]
{
    // XCD-banded: xcd = bid&7 owns panels [xcd*72, xcd*72+72)
    const int bid = blockIdx.x;            // 0..767
    const int xcd = bid & 7;
    const int j   = bid >> 3;              // 0..95
    const int t = threadIdx.x, lane = t & 63, w = t >> 6;   // w: 0..15
    const int j2  = j * 4 + (w >> 2);      // 0..383 (old block id)
    const int w2  = w & 3;                 // old wave slot
    const int strip = j2 & 63;             // 32-row strip
    const int pg    = xcd * 6 + (j2 >> 6); // 0..47 (12 panels each)

    const int g = lane >> 4, ci = lane & 15;

    // ---- A fragments in registers (32 rows x 256 K fp8 = 32 VGPR) ----
    const long* Ap = (const long*)(Abuf + ((size_t)strip << 13));
    long a[2][8];
    #pragma unroll
    for (int mi = 0; mi < 2; ++mi)
        #pragma unroll
        for (int ks = 0; ks < 8; ++ks)
            a[mi][ks] = Ap[((mi << 3) | ks) * 64 + lane];

    #pragma unroll 1
    for (int pi = 0; pi < 3; ++pi) {
        const int p = pg * 12 + w2 * 3 + pi;
        const long* Bp = (const long*)(Bbuf + ((size_t)p << 14));
        float rs[2][4] = {};
        #pragma unroll
        for (int nh = 0; nh < 2; ++nh) {           // two ni-pairs
            long b[2][8];
            #pragma unroll
            for (int nn = 0; nn < 2; ++nn)
                #pragma unroll
                for (int ks = 0; ks < 8; ++ks)
                    b[nn][ks] = Bp[((((nh << 1) | nn) << 3) | ks) * 64 + lane];
            f32x4 acc[2][2] = {};
            #pragma unroll
            for (int ks = 0; ks < 8; ++ks)
                #pragma unroll
                for (int nn = 0; nn < 2; ++nn) {
                    acc[0][nn] = __builtin_amdgcn_mfma_f32_16x16x32_fp8_fp8(
                        a[0][ks], b[nn][ks], acc[0][nn], 0, 0, 0);
                    acc[1][nn] = __builtin_amdgcn_mfma_f32_16x16x32_fp8_fp8(
                        a[1][ks], b[nn][ks], acc[1][nn], 0, 0, 0);
                }
            #pragma unroll
            for (int mi = 0; mi < 2; ++mi)
                #pragma unroll
                for (int rj = 0; rj < 4; ++rj)
                    rs[mi][rj] += __builtin_exp2f(acc[mi][0][rj])
                                + __builtin_exp2f(acc[mi][1][rj]);
        }
        #pragma unroll
        for (int mi = 0; mi < 2; ++mi)
            #pragma unroll
            for (int rj = 0; rj < 4; ++rj) {
                const float v = rowsum16(rs[mi][rj]);
                if (ci == 0)
                    partS[(size_t)(strip * 32 + mi * 16 + g * 4 + rj) * NPAN + p] = v;
            }
    }
}

// Pass 3: ONE WAVE PER ROW (512 blocks x 4 waves). Coalesced partS reads,
// float4 X.csum dot (Lp = 10*dot), diag dot for class-1; shuffle reduce.
__global__ __launch_bounds__(256) void pass3_kernel(
    const int* __restrict__ y,
    const float* __restrict__ partS, const float* __restrict__ csum,
    const float* __restrict__ X, const float* __restrict__ Q,
    float* __restrict__ out)
{
    __shared__ float sh[4];
    const int t = threadIdx.x, lane = t & 63, w = t >> 6;
    const int r = blockIdx.x * 4 + w;
    const int c = y[r & 255];

    const float* ps = partS + (size_t)r * NPAN;
    float S = 0.0f, E1 = 0.0f;
    const int p0 = (c - 1) * 32, p1 = c * 32;
    #pragma unroll
    for (int i = 0; i < 9; ++i) {
        const int p = i * 64 + lane;
        const float v = ps[p];
        S += v;
        if (p >= p0 && p < p1) E1 += v;
    }
    const float* Xrow = X + ((size_t)((r & 255) * 8 + (r >> 8))) * FEAT;
    const float4_t xv = ((const float4_t*)Xrow)[lane];
    const float4_t cv = ((const float4_t*)(csum + (size_t)(c - 1) * FEAT))[lane];
    float dot = xv.x * cv.x + xv.y * cv.y + xv.z * cv.z + xv.w * cv.w;
    if (c == 1) {
        const float4_t qv = ((const float4_t*)(Q + ((size_t)(BANK + r)) * FEAT))[lane];
        dot -= xv.x * qv.x + xv.y * qv.y + xv.z * qv.z + xv.w * qv.w;
    }
    #pragma unroll
    for (int mm = 1; mm < 64; mm <<= 1) {
        S   += __shfl_xor(S, mm);
        E1  += __shfl_xor(E1, mm);
        dot += __shfl_xor(dot, mm);
    }
    if (lane == 0) {
        const float m = (c == 1) ? 2047.0f : 2048.0f;
        const float neg = S - E1 + 2048.0f;
        sh[w] = __logf(neg) - 10.0f * dot / m;
    }
    __syncthreads();
    if (t == 0)
        atomicAdd(out, (sh[0] + sh[1] + sh[2] + sh[3]) * (1.0f / (float)NROWS));
}

extern "C" void kernel_launch(void* const* d_in, const int* in_sizes, int n_in,
                              void* d_out, int out_size, void* d_ws, size_t ws_size,
                              hipStream_t stream) {
    const float* X = (const float*)d_in[0];
    const int*   y = (const int*)d_in[1];
    const float* Q = (const float*)d_in[2];
    float* out   = (float*)d_out;
    float* partS = (float*)d_ws;                                // 2048*576 f32 (4.72 MB)
    float* csum  = partS + (size_t)NROWS * NPAN;                // 18*256 f32 (18 KB)
    unsigned char* Abuf = (unsigned char*)(csum + NCLS * FEAT); // 512 KB
    unsigned char* Bbuf = Abuf + ((size_t)A_CH8 << 3);          // 9.44 MB

    pass0_pack<<<dim3(TOT8 / 256), dim3(256), 0, stream>>>(X, Q, Abuf, Bbuf, csum, out);
    pass2_csum<<<dim3(NCLS * CSPLIT), dim3(256), 0, stream>>>(Q, csum);
    pass1_gemm<<<dim3(768), dim3(1024), 0, stream>>>(Abuf, Bbuf, partS);
    pass3_kernel<<<dim3(NROWS / 4), dim3(256), 0, stream>>>(y, partS, csum, X, Q, out);
}

// Round 17
// 79.817 us; speedup vs baseline: 2.0296x; 2.0296x over previous
//
#include <hip/hip_runtime.h>
#include <hip/hip_fp8.h>

typedef float  float4_t __attribute__((ext_vector_type(4)));
typedef unsigned int uint2_t __attribute__((ext_vector_type(2)));
typedef float  f32x4   __attribute__((ext_vector_type(4)));

#define FEAT   256
#define BANK   2048
#define NROWS  2048       // 256 anchors * 8 views
#define NPAN   576        // 64-col panels over 36864 cols
#define NCLS   18
#define CSPLIT 16         // m-chunks per class for csum atomics
#define EXP2K  14.4269504088896f   // 10*log2(e); A pre-scaled -> exp(10 dot)=exp2(acc)
#define A_CH8  65536      // A 8-byte chunks: 64 strips * 2 mi * 8 ks * 64 lanes
#define B_CH8  1179648    // B 8-byte chunks: 576 panels * 32 frags * 64 lanes
#define TOT8   (A_CH8 + B_CH8)

__device__ inline unsigned char to_fp8(float x) {
    __hip_fp8_e4m3 f(x);
    return *reinterpret_cast<unsigned char*>(&f);
}

// 16-lane (DPP row) sum: every lane of each 16-lane group gets the group total.
__device__ inline float rowsum16(float x) {
    float t;
    asm("s_nop 1\n\tv_add_f32 %0, %1, %1 row_ror:1"  : "=v"(t) : "v"(x)); x = t;
    asm("s_nop 1\n\tv_add_f32 %0, %1, %1 row_ror:2"  : "=v"(t) : "v"(x)); x = t;
    asm("s_nop 1\n\tv_add_f32 %0, %1, %1 row_ror:4"  : "=v"(t) : "v"(x)); x = t;
    asm("s_nop 1\n\tv_add_f32 %0, %1, %1 row_ror:8"  : "=v"(t) : "v"(x)); x = t;
    return x;
}

// Pass 0: fp32 -> fp8 e4m3 ONCE, MFMA fragment order; A pre-scaled by EXP2K.
// Also zeroes out[0] and csum[18*256].
__global__ __launch_bounds__(256) void pass0_pack(
    const float* __restrict__ X,    // X_anchor [256][8][256]
    const float* __restrict__ Q,    // queue [19][2048][256]
    unsigned char* __restrict__ Abuf,
    unsigned char* __restrict__ Bbuf,
    float* __restrict__ csum,
    float* __restrict__ out)
{
    const int cid = blockIdx.x * 256 + threadIdx.x;
    if (cid == 0) out[0] = 0.0f;
    if (cid < NCLS * FEAT) csum[cid] = 0.0f;
    if (cid >= TOT8) return;
    const int lane = cid & 63;
    const int ks   = (cid >> 6) & 7;
    const int k    = ks * 32 + ((lane >> 4) << 3);
    const float* src;
    unsigned char* dst;
    float scale;
    if (cid < A_CH8) {
        const int mi = (cid >> 9) & 1, s = cid >> 10;
        const int r  = s * 32 + mi * 16 + (lane & 15);      // anchor row = v*256+a
        src = X + ((size_t)((r & 255) * 8 + (r >> 8))) * FEAT + k;
        dst = Abuf + ((size_t)cid << 3);
        scale = EXP2K;
    } else {
        const int b = cid - A_CH8;
        const int ni = (b >> 9) & 3, p = b >> 11;
        const int col = p * 64 + ni * 16 + (lane & 15);     // class 0 skipped
        src = Q + ((size_t)(BANK + col)) * FEAT + k;
        dst = Bbuf + ((size_t)b << 3);
        scale = 1.0f;
    }
    float4_t v0 = *(const float4_t*)src;
    float4_t v1 = *(const float4_t*)(src + 4);
    const unsigned int b0 = to_fp8(v0.x * scale) | ((unsigned int)to_fp8(v0.y * scale) << 8)
                          | ((unsigned int)to_fp8(v0.z * scale) << 16) | ((unsigned int)to_fp8(v0.w * scale) << 24);
    const unsigned int b1 = to_fp8(v1.x * scale) | ((unsigned int)to_fp8(v1.y * scale) << 8)
                          | ((unsigned int)to_fp8(v1.z * scale) << 16) | ((unsigned int)to_fp8(v1.w * scale) << 24);
    uint2_t u = { b0, b1 };
    *(uint2_t*)dst = u;
}

// Pass 2: per-class column sums of Q (f32), 16 m-chunks per class, atomicAdd
// into csum[c][k].
__global__ __launch_bounds__(256) void pass2_csum(
    const float* __restrict__ Q, float* __restrict__ csum)
{
    const int c = blockIdx.x >> 4;        // 0..17 -> class c+1
    const int i = blockIdx.x & 15;
    const int k = threadIdx.x;
    const float* base = Q + ((size_t)(c + 1) * BANK + (size_t)i * (BANK / CSPLIT)) * FEAT + k;
    float s = 0.0f;
    #pragma unroll 4
    for (int m = 0; m < BANK / CSPLIT; ++m) s += base[(size_t)m * FEAT];
    atomicAdd(&csum[c * FEAT + k], s);
}

// Pass 1: barrier-free streaming fp8 GEMM, R15 per-wave structure, but
// 128-thread blocks (2 waves) for finer dispatch packing. VGPR cap 128
// (launch_bounds(128,4)) = R15's proven budget; NO forced higher occupancy.
__global__ __launch_bounds__(128, 4) void pass1_gemm(
    const unsigned char* __restrict__ Abuf,
    const unsigned char* __restrict__ Bbuf,
    float* __restrict__ partS)  // [NROWS][NPAN]
{
    // XCD-banded: xcd = bid&7 owns panel slots [xcd*24, xcd*24+24)
    const int bid = blockIdx.x;            // 0..6143
    const int xcd = bid & 7;
    const int j   = bid >> 3;              // 0..767
    const int t = threadIdx.x, lane = t & 63, w = t >> 6;   // w: 0..1
    const int u = j * 2 + w;               // 0..1535 within xcd
    const int strip = u & 63;              // 32-row strip
    const int slot  = xcd * 24 + (u >> 6); // 0..191 (3 panels each)

    const int g = lane >> 4, ci = lane & 15;

    // ---- A fragments in registers (32 rows x 256 K fp8 = 32 VGPR) ----
    const long* Ap = (const long*)(Abuf + ((size_t)strip << 13));
    long a[2][8];
    #pragma unroll
    for (int mi = 0; mi < 2; ++mi)
        #pragma unroll
        for (int ks = 0; ks < 8; ++ks)
            a[mi][ks] = Ap[((mi << 3) | ks) * 64 + lane];

    #pragma unroll 1
    for (int pi = 0; pi < 3; ++pi) {
        const int p = slot * 3 + pi;
        const long* Bp = (const long*)(Bbuf + ((size_t)p << 14));
        float rs[2][4] = {};
        #pragma unroll
        for (int nh = 0; nh < 2; ++nh) {           // two ni-pairs
            long b[2][8];
            #pragma unroll
            for (int nn = 0; nn < 2; ++nn)
                #pragma unroll
                for (int ks = 0; ks < 8; ++ks)
                    b[nn][ks] = Bp[((((nh << 1) | nn) << 3) | ks) * 64 + lane];
            f32x4 acc[2][2] = {};
            #pragma unroll
            for (int ks = 0; ks < 8; ++ks)
                #pragma unroll
                for (int nn = 0; nn < 2; ++nn) {
                    acc[0][nn] = __builtin_amdgcn_mfma_f32_16x16x32_fp8_fp8(
                        a[0][ks], b[nn][ks], acc[0][nn], 0, 0, 0);
                    acc[1][nn] = __builtin_amdgcn_mfma_f32_16x16x32_fp8_fp8(
                        a[1][ks], b[nn][ks], acc[1][nn], 0, 0, 0);
                }
            #pragma unroll
            for (int mi = 0; mi < 2; ++mi)
                #pragma unroll
                for (int rj = 0; rj < 4; ++rj)
                    rs[mi][rj] += __builtin_exp2f(acc[mi][0][rj])
                                + __builtin_exp2f(acc[mi][1][rj]);
        }
        #pragma unroll
        for (int mi = 0; mi < 2; ++mi)
            #pragma unroll
            for (int rj = 0; rj < 4; ++rj) {
                const float v = rowsum16(rs[mi][rj]);
                if (ci == 0)
                    partS[(size_t)(strip * 32 + mi * 16 + g * 4 + rj) * NPAN + p] = v;
            }
    }
}

// Pass 3: ONE WAVE PER ROW (512 blocks x 4 waves). Coalesced partS[r][p]
// reads, float4 X.csum dot (Lp = 10*dot), diag dot for class-1; shuffle reduce.
__global__ __launch_bounds__(256) void pass3_kernel(
    const int* __restrict__ y,
    const float* __restrict__ partS, const float* __restrict__ csum,
    const float* __restrict__ X, const float* __restrict__ Q,
    float* __restrict__ out)
{
    __shared__ float sh[4];
    const int t = threadIdx.x, lane = t & 63, w = t >> 6;
    const int r = blockIdx.x * 4 + w;
    const int c = y[r & 255];

    const float* ps = partS + (size_t)r * NPAN;
    float S = 0.0f, E1 = 0.0f;
    const int p0 = (c - 1) * 32, p1 = c * 32;
    #pragma unroll
    for (int i = 0; i < 9; ++i) {
        const int p = i * 64 + lane;
        const float v = ps[p];
        S += v;
        if (p >= p0 && p < p1) E1 += v;
    }
    const float* Xrow = X + ((size_t)((r & 255) * 8 + (r >> 8))) * FEAT;
    const float4_t xv = ((const float4_t*)Xrow)[lane];
    const float4_t cv = ((const float4_t*)(csum + (size_t)(c - 1) * FEAT))[lane];
    float dot = xv.x * cv.x + xv.y * cv.y + xv.z * cv.z + xv.w * cv.w;
    if (c == 1) {
        const float4_t qv = ((const float4_t*)(Q + ((size_t)(BANK + r)) * FEAT))[lane];
        dot -= xv.x * qv.x + xv.y * qv.y + xv.z * qv.z + xv.w * qv.w;
    }
    #pragma unroll
    for (int mm = 1; mm < 64; mm <<= 1) {
        S   += __shfl_xor(S, mm);
        E1  += __shfl_xor(E1, mm);
        dot += __shfl_xor(dot, mm);
    }
    if (lane == 0) {
        const float m = (c == 1) ? 2047.0f : 2048.0f;
        const float neg = S - E1 + 2048.0f;
        sh[w] = __logf(neg) - 10.0f * dot / m;
    }
    __syncthreads();
    if (t == 0)
        atomicAdd(out, (sh[0] + sh[1] + sh[2] + sh[3]) * (1.0f / (float)NROWS));
}

extern "C" void kernel_launch(void* const* d_in, const int* in_sizes, int n_in,
                              void* d_out, int out_size, void* d_ws, size_t ws_size,
                              hipStream_t stream) {
    const float* X = (const float*)d_in[0];
    const int*   y = (const int*)d_in[1];
    const float* Q = (const float*)d_in[2];
    float* out   = (float*)d_out;
    float* partS = (float*)d_ws;                                // 2048*576 f32 (4.72 MB)
    float* csum  = partS + (size_t)NROWS * NPAN;                // 18*256 f32 (18 KB)
    unsigned char* Abuf = (unsigned char*)(csum + NCLS * FEAT); // 512 KB
    unsigned char* Bbuf = Abuf + ((size_t)A_CH8 << 3);          // 9.44 MB

    pass0_pack<<<dim3(TOT8 / 256), dim3(256), 0, stream>>>(X, Q, Abuf, Bbuf, csum, out);
    pass2_csum<<<dim3(NCLS * CSPLIT), dim3(256), 0, stream>>>(Q, csum);
    pass1_gemm<<<dim3(6144), dim3(128), 0, stream>>>(Abuf, Bbuf, partS);
    pass3_kernel<<<dim3(NROWS / 4), dim3(256), 0, stream>>>(y, partS, csum, X, Q, out);
}

// Round 18
// 71.276 us; speedup vs baseline: 2.2728x; 1.1198x over previous
//
#include <hip/hip_runtime.h>
#include <hip/hip_fp8.h>

typedef float  float4_t __attribute__((ext_vector_type(4)));
typedef unsigned int uint2_t __attribute__((ext_vector_type(2)));
typedef float  f32x4   __attribute__((ext_vector_type(4)));

#define FEAT   256
#define BANK   2048
#define NROWS  2048       // 256 anchors * 8 views
#define NPAN   576        // 64-col panels over 36864 cols
#define NCLS   18
#define CSPLIT 16         // m-chunks per class for csum atomics
#define EXP2K  14.4269504088896f   // 10*log2(e); A pre-scaled -> exp(10 dot)=exp2(acc)
#define A_CH8  65536      // A 8-byte chunks: 32 strips * 4 mi * 8 ks * 64 lanes
#define B_CH8  1179648    // B 8-byte chunks: 576 panels * 32 frags * 64 lanes
#define TOT8   (A_CH8 + B_CH8)

__device__ inline unsigned char to_fp8(float x) {
    __hip_fp8_e4m3 f(x);
    return *reinterpret_cast<unsigned char*>(&f);
}

// 16-lane (DPP row) sum: every lane of each 16-lane group gets the group total.
__device__ inline float rowsum16(float x) {
    float t;
    asm("s_nop 1\n\tv_add_f32 %0, %1, %1 row_ror:1"  : "=v"(t) : "v"(x)); x = t;
    asm("s_nop 1\n\tv_add_f32 %0, %1, %1 row_ror:2"  : "=v"(t) : "v"(x)); x = t;
    asm("s_nop 1\n\tv_add_f32 %0, %1, %1 row_ror:4"  : "=v"(t) : "v"(x)); x = t;
    asm("s_nop 1\n\tv_add_f32 %0, %1, %1 row_ror:8"  : "=v"(t) : "v"(x)); x = t;
    return x;
}

// Pass 0: fp32 -> fp8 e4m3 ONCE, MFMA fragment order; A pre-scaled by EXP2K.
// A strips are 64 rows now: cid = s*2048 + mi*512 + ks*64 + lane;
//   row = s*64 + mi*16 + (lane&15), k = ks*32 + (lane>>4)*8.
// Also zeroes out[0] and csum[18*256].
__global__ __launch_bounds__(256) void pass0_pack(
    const float* __restrict__ X,    // X_anchor [256][8][256]
    const float* __restrict__ Q,    // queue [19][2048][256]
    unsigned char* __restrict__ Abuf,
    unsigned char* __restrict__ Bbuf,
    float* __restrict__ csum,
    float* __restrict__ out)
{
    const int cid = blockIdx.x * 256 + threadIdx.x;
    if (cid == 0) out[0] = 0.0f;
    if (cid < NCLS * FEAT) csum[cid] = 0.0f;
    if (cid >= TOT8) return;
    const int lane = cid & 63;
    const int ks   = (cid >> 6) & 7;
    const int k    = ks * 32 + ((lane >> 4) << 3);
    const float* src;
    unsigned char* dst;
    float scale;
    if (cid < A_CH8) {
        const int mi = (cid >> 9) & 3, s = cid >> 11;
        const int r  = s * 64 + mi * 16 + (lane & 15);      // anchor row = v*256+a
        src = X + ((size_t)((r & 255) * 8 + (r >> 8))) * FEAT + k;
        dst = Abuf + ((size_t)cid << 3);
        scale = EXP2K;
    } else {
        const int b = cid - A_CH8;
        const int ni = (b >> 9) & 3, p = b >> 11;
        const int col = p * 64 + ni * 16 + (lane & 15);     // class 0 skipped
        src = Q + ((size_t)(BANK + col)) * FEAT + k;
        dst = Bbuf + ((size_t)b << 3);
        scale = 1.0f;
    }
    float4_t v0 = *(const float4_t*)src;
    float4_t v1 = *(const float4_t*)(src + 4);
    const unsigned int b0 = to_fp8(v0.x * scale) | ((unsigned int)to_fp8(v0.y * scale) << 8)
                          | ((unsigned int)to_fp8(v0.z * scale) << 16) | ((unsigned int)to_fp8(v0.w * scale) << 24);
    const unsigned int b1 = to_fp8(v1.x * scale) | ((unsigned int)to_fp8(v1.y * scale) << 8)
                          | ((unsigned int)to_fp8(v1.z * scale) << 16) | ((unsigned int)to_fp8(v1.w * scale) << 24);
    uint2_t u = { b0, b1 };
    *(uint2_t*)dst = u;
}

// Pass 2: per-class column sums of Q (f32), 16 m-chunks per class, atomicAdd
// into csum[c][k].
__global__ __launch_bounds__(256) void pass2_csum(
    const float* __restrict__ Q, float* __restrict__ csum)
{
    const int c = blockIdx.x >> 4;        // 0..17 -> class c+1
    const int i = blockIdx.x & 15;
    const int k = threadIdx.x;
    const float* base = Q + ((size_t)(c + 1) * BANK + (size_t)i * (BANK / CSPLIT)) * FEAT + k;
    float s = 0.0f;
    #pragma unroll 4
    for (int m = 0; m < BANK / CSPLIT; ++m) s += base[(size_t)m * FEAT];
    atomicAdd(&csum[c * FEAT + k], s);
}

// Pass 1: barrier-free streaming fp8 GEMM, 64 ROWS PER WAVE (halves B L2
// traffic vs R17). a[4][8]=64 VGPR pinned; per-ni single-buffer b[8]=16;
// acc[4]=16; rs[4][4]=16 -> ~115 VGPR, 4 waves/SIMD. 2-wave blocks.
__global__ __launch_bounds__(128, 4) void pass1_gemm(
    const unsigned char* __restrict__ Abuf,
    const unsigned char* __restrict__ Bbuf,
    float* __restrict__ partS)  // [NROWS][NPAN]
{
    // XCD-banded: xcd = bid&7 owns panel slots [xcd*24, xcd*24+24)
    const int bid = blockIdx.x;            // 0..3071
    const int xcd = bid & 7;
    const int j   = bid >> 3;              // 0..383
    const int t = threadIdx.x, lane = t & 63, w = t >> 6;   // w: 0..1
    const int u = j * 2 + w;               // 0..767 within xcd
    const int strip = u & 31;              // 64-row strip
    const int slot  = xcd * 24 + (u >> 5); // 0..191 (3 panels each)

    const int g = lane >> 4, ci = lane & 15;

    // ---- A fragments in registers (64 rows x 256 K fp8 = 64 VGPR) ----
    const long* Ap = (const long*)(Abuf + ((size_t)strip << 14));
    long a[4][8];
    #pragma unroll
    for (int mi = 0; mi < 4; ++mi)
        #pragma unroll
        for (int ks = 0; ks < 8; ++ks)
            a[mi][ks] = Ap[((mi << 3) | ks) * 64 + lane];

    #pragma unroll 1
    for (int pi = 0; pi < 3; ++pi) {
        const int p = slot * 3 + pi;
        const long* Bp = (const long*)(Bbuf + ((size_t)p << 14));
        float rs[4][4] = {};
        #pragma unroll 1
        for (int nn = 0; nn < 4; ++nn) {           // one ni at a time: b[8]=16 VGPR
            long b[8];
            #pragma unroll
            for (int ks = 0; ks < 8; ++ks)
                b[ks] = Bp[((nn << 3) | ks) * 64 + lane];
            f32x4 acc[4] = {};
            #pragma unroll
            for (int ks = 0; ks < 8; ++ks) {
                acc[0] = __builtin_amdgcn_mfma_f32_16x16x32_fp8_fp8(a[0][ks], b[ks], acc[0], 0, 0, 0);
                acc[1] = __builtin_amdgcn_mfma_f32_16x16x32_fp8_fp8(a[1][ks], b[ks], acc[1], 0, 0, 0);
                acc[2] = __builtin_amdgcn_mfma_f32_16x16x32_fp8_fp8(a[2][ks], b[ks], acc[2], 0, 0, 0);
                acc[3] = __builtin_amdgcn_mfma_f32_16x16x32_fp8_fp8(a[3][ks], b[ks], acc[3], 0, 0, 0);
            }
            #pragma unroll
            for (int mi = 0; mi < 4; ++mi)
                #pragma unroll
                for (int rj = 0; rj < 4; ++rj)
                    rs[mi][rj] += __builtin_exp2f(acc[mi][rj]);
        }
        #pragma unroll
        for (int mi = 0; mi < 4; ++mi)
            #pragma unroll
            for (int rj = 0; rj < 4; ++rj) {
                const float v = rowsum16(rs[mi][rj]);
                if (ci == 0)
                    partS[(size_t)(strip * 64 + mi * 16 + g * 4 + rj) * NPAN + p] = v;
            }
    }
}

// Pass 3: ONE WAVE PER ROW (512 blocks x 4 waves). Coalesced partS[r][p]
// reads, float4 X.csum dot (Lp = 10*dot), diag dot for class-1; shuffle reduce.
__global__ __launch_bounds__(256) void pass3_kernel(
    const int* __restrict__ y,
    const float* __restrict__ partS, const float* __restrict__ csum,
    const float* __restrict__ X, const float* __restrict__ Q,
    float* __restrict__ out)
{
    __shared__ float sh[4];
    const int t = threadIdx.x, lane = t & 63, w = t >> 6;
    const int r = blockIdx.x * 4 + w;
    const int c = y[r & 255];

    const float* ps = partS + (size_t)r * NPAN;
    float S = 0.0f, E1 = 0.0f;
    const int p0 = (c - 1) * 32, p1 = c * 32;
    #pragma unroll
    for (int i = 0; i < 9; ++i) {
        const int p = i * 64 + lane;
        const float v = ps[p];
        S += v;
        if (p >= p0 && p < p1) E1 += v;
    }
    const float* Xrow = X + ((size_t)((r & 255) * 8 + (r >> 8))) * FEAT;
    const float4_t xv = ((const float4_t*)Xrow)[lane];
    const float4_t cv = ((const float4_t*)(csum + (size_t)(c - 1) * FEAT))[lane];
    float dot = xv.x * cv.x + xv.y * cv.y + xv.z * cv.z + xv.w * cv.w;
    if (c == 1) {
        const float4_t qv = ((const float4_t*)(Q + ((size_t)(BANK + r)) * FEAT))[lane];
        dot -= xv.x * qv.x + xv.y * qv.y + xv.z * qv.z + xv.w * qv.w;
    }
    #pragma unroll
    for (int mm = 1; mm < 64; mm <<= 1) {
        S   += __shfl_xor(S, mm);
        E1  += __shfl_xor(E1, mm);
        dot += __shfl_xor(dot, mm);
    }
    if (lane == 0) {
        const float m = (c == 1) ? 2047.0f : 2048.0f;
        const float neg = S - E1 + 2048.0f;
        sh[w] = __logf(neg) - 10.0f * dot / m;
    }
    __syncthreads();
    if (t == 0)
        atomicAdd(out, (sh[0] + sh[1] + sh[2] + sh[3]) * (1.0f / (float)NROWS));
}

extern "C" void kernel_launch(void* const* d_in, const int* in_sizes, int n_in,
                              void* d_out, int out_size, void* d_ws, size_t ws_size,
                              hipStream_t stream) {
    const float* X = (const float*)d_in[0];
    const int*   y = (const int*)d_in[1];
    const float* Q = (const float*)d_in[2];
    float* out   = (float*)d_out;
    float* partS = (float*)d_ws;                                // 2048*576 f32 (4.72 MB)
    float* csum  = partS + (size_t)NROWS * NPAN;                // 18*256 f32 (18 KB)
    unsigned char* Abuf = (unsigned char*)(csum + NCLS * FEAT); // 512 KB
    unsigned char* Bbuf = Abuf + ((size_t)A_CH8 << 3);          // 9.44 MB

    pass0_pack<<<dim3(TOT8 / 256), dim3(256), 0, stream>>>(X, Q, Abuf, Bbuf, csum, out);
    pass2_csum<<<dim3(NCLS * CSPLIT), dim3(256), 0, stream>>>(Q, csum);
    pass1_gemm<<<dim3(3072), dim3(128), 0, stream>>>(Abuf, Bbuf, partS);
    pass3_kernel<<<dim3(NROWS / 4), dim3(256), 0, stream>>>(y, partS, csum, X, Q, out);
}